// Round 3
// baseline (783.987 us; speedup 1.0000x reference)
//
#include <hip/hip_runtime.h>
#include <math.h>

#define BATCH 8
#define TPH   512
#define TMEL  4096
#define HCH   256
#define WLEN  256
#define KKTOT 1280

// ws offsets (in doubles)
#define OFF_WT1 0          // 1280*256
#define OFF_WT2 327680     // 1280*256
#define OFF_H1  655360     // 4096*256
#define OFF_H2  1703936    // 4096*256
#define OFF_M   2752512    // 4096
#define OFF_CEN 2756608    // 4096

// transpose weights (O,I,K) -> (k*256+i, o), f32 -> f64
__global__ __launch_bounds__(256) void k_transpose_w(const float* __restrict__ w1,
                                                     const float* __restrict__ w2,
                                                     double* __restrict__ wt1,
                                                     double* __restrict__ wt2) {
    int idx = blockIdx.x;
    const float* src; double* dst; int kk;
    if (idx < KKTOT) { src = w1; dst = wt1; kk = idx; }
    else             { src = w2; dst = wt2; kk = idx - KKTOT; }
    int k = kk >> 8, i = kk & 255, o = threadIdx.x;
    dst[kk * HCH + o] = (double)src[o * KKTOT + i * 5 + k];
}

// full-f64 conv-as-GEMM: M=4096 (b*512+t), N=256, K=1280 (k*256+i)
// A[m,kk] = (f64)src[b, t+k-2, i] * (f64)mask[b, t+k-2]  (zero-padded per batch)
template <typename TS>
__global__ __launch_bounds__(256) void k_conv_gemm(const TS* __restrict__ src,
                                                   const float* __restrict__ mask,
                                                   const double* __restrict__ wT,
                                                   double* __restrict__ out) {
    __shared__ double As[16][68];
    __shared__ double Bs[16][64];
    int tid = threadIdx.x;
    int ty = tid >> 4, tx = tid & 15;
    int m0 = blockIdx.x * 64;
    int c0 = blockIdx.y * 64;
    int la_k = tid & 15, la_m0 = tid >> 4;
    int lb_c = tid & 63, lb_k0 = tid >> 6;
    double acc[4][4];
#pragma unroll
    for (int i = 0; i < 4; i++)
#pragma unroll
        for (int j = 0; j < 4; j++) acc[i][j] = 0.0;

    for (int kb = 0; kb < KKTOT; kb += 16) {
        int kk = kb + la_k;
        int k5 = kk >> 8, ci = kk & 255;
#pragma unroll
        for (int j = 0; j < 4; j++) {
            int mm = la_m0 + j * 16;
            int m = m0 + mm;
            int tt = (m & 511) + k5 - 2;
            double v = 0.0;
            if ((unsigned)tt < 512u) {
                int r = (m & ~511) + tt;
                v = (double)src[r * HCH + ci] * (double)mask[r];
            }
            As[la_k][mm] = v;
        }
#pragma unroll
        for (int j = 0; j < 4; j++) {
            int kkk = lb_k0 + j * 4;
            Bs[kkk][lb_c] = wT[(kb + kkk) * HCH + c0 + lb_c];
        }
        __syncthreads();
#pragma unroll
        for (int k = 0; k < 16; k++) {
            double a0 = As[k][ty * 4 + 0], a1 = As[k][ty * 4 + 1];
            double a2 = As[k][ty * 4 + 2], a3 = As[k][ty * 4 + 3];
            double b0 = Bs[k][tx * 4 + 0], b1 = Bs[k][tx * 4 + 1];
            double b2 = Bs[k][tx * 4 + 2], b3 = Bs[k][tx * 4 + 3];
            acc[0][0] += a0 * b0; acc[0][1] += a0 * b1; acc[0][2] += a0 * b2; acc[0][3] += a0 * b3;
            acc[1][0] += a1 * b0; acc[1][1] += a1 * b1; acc[1][2] += a1 * b2; acc[1][3] += a1 * b3;
            acc[2][0] += a2 * b0; acc[2][1] += a2 * b1; acc[2][2] += a2 * b2; acc[2][3] += a2 * b3;
            acc[3][0] += a3 * b0; acc[3][1] += a3 * b1; acc[3][2] += a3 * b2; acc[3][3] += a3 * b3;
        }
        __syncthreads();
    }
#pragma unroll
    for (int r = 0; r < 4; r++) {
        int m = m0 + ty * 4 + r;
        double* op = out + m * HCH + c0 + tx * 4;
#pragma unroll
        for (int j = 0; j < 4; j++) op[j] = acc[r][j];
    }
}

// f64: v = y + bias; channel-LN over 256; relu. In-place OK.
__global__ __launch_bounds__(256) void k_ln_relu(const double* __restrict__ y,
                                                 const float* __restrict__ bias,
                                                 const float* __restrict__ g,
                                                 const float* __restrict__ b,
                                                 double* __restrict__ out) {
    __shared__ double red[256];
    int row = blockIdx.x, tid = threadIdx.x;
    double v = y[row * HCH + tid] + (double)bias[tid];
    red[tid] = v; __syncthreads();
    for (int s = 128; s > 0; s >>= 1) { if (tid < s) red[tid] += red[tid + s]; __syncthreads(); }
    double mu = red[0] * (1.0 / 256.0); __syncthreads();
    double w = v - mu;
    red[tid] = w * w; __syncthreads();
    for (int s = 128; s > 0; s >>= 1) { if (tid < s) red[tid] += red[tid + s]; __syncthreads(); }
    double var = red[0] * (1.0 / 256.0);
    double o = w * (1.0 / sqrt(var + 1e-4)) * (double)g[tid] + (double)b[tid];
    out[row * HCH + tid] = fmax(o, 0.0);
}

// f64: explicit proj conv + gauss conv ch0 -> m[row]
__global__ __launch_bounds__(256) void k_m(const float* __restrict__ x,
                                           const double* __restrict__ h2,
                                           const float* __restrict__ projw,
                                           const float* __restrict__ projb,
                                           const float* __restrict__ gw,
                                           const float* __restrict__ gb,
                                           const float* __restrict__ mask,
                                           double* __restrict__ mbuf) {
    __shared__ double h2s[256];
    __shared__ double red[256];
    int row = blockIdx.x, tid = threadIdx.x;
    h2s[tid] = h2[row * HCH + tid];
    __syncthreads();
    double pc = 0.0;
    const float* pw = projw + tid * HCH;
#pragma unroll 4
    for (int i = 0; i < HCH; i++) pc += (double)pw[i] * h2s[i];
    double hb = pc + (double)projb[tid];               // conv + bias
    double hc = ((double)x[row * HCH + tid] + hb) * (double)mask[row];  // (xt + conv)*mt
    red[tid] = (double)gw[tid] * hc;
    __syncthreads();
    for (int s = 128; s > 0; s >>= 1) { if (tid < s) red[tid] += red[tid + s]; __syncthreads(); }
    if (tid == 0) {
        double g0 = red[0] + (double)gb[0];
        double mm = fmax(g0, 0.0) + 1.0;
        mbuf[row] = mm * (double)mask[row];
    }
}

// per-batch f64: deterministic dur scatter (mirrors np.add.at order), mel counts,
// scale, msc, sequential cumsum -> centers; m_word out (f32)
__global__ __launch_bounds__(512) void k_dur(const double* __restrict__ mbuf,
                                             const int* __restrict__ x2w,
                                             const int* __restrict__ m2w,
                                             double* __restrict__ center,
                                             float* __restrict__ out_mword) {
    __shared__ double ms[512];
    __shared__ int xw[512];
    __shared__ double dur[257];
    __shared__ int cntw[257];
    __shared__ double msc[512], cbuf[512];
    int b = blockIdx.x, tid = threadIdx.x;
    if (tid < 257) cntw[tid] = 0;
    ms[tid] = mbuf[b * TPH + tid];
    {
        int w = x2w[b * TPH + tid];
        xw[tid] = max(0, min(256, w));
    }
    __syncthreads();
    for (int j = 0; j < TMEL / 512; j++) {
        int ww = m2w[b * TMEL + tid + j * 512];
        ww = max(0, min(256, ww));
        atomicAdd(&cntw[ww], 1);                       // integer counts: exact any order
    }
    __syncthreads();
    if (tid >= 1 && tid <= 256) {
        double s = 0.0;
        for (int t = 0; t < TPH; t++) {                // sequential t-order = np.add.at
            if (xw[t] == tid) s += ms[t];
        }
        dur[tid] = s;
        out_mword[b * WLEN + tid - 1] = (float)s;
    }
    __syncthreads();
    {
        int w = xw[tid];
        double sc = (double)cntw[w] / (dur[w] + 1e-4);
        msc[tid] = ms[tid] + (sc - 1.0) * ms[tid];
    }
    __syncthreads();
    if (tid == 0) {
        double run = 0.0;
        for (int t = 0; t < TPH; t++) {                // sequential = np.cumsum
            run += msc[t];
            cbuf[t] = run - msc[t] * 0.5;
        }
    }
    __syncthreads();
    center[b * TPH + tid] = cbuf[tid];
}

// one block per (b, mel) row: f64 masked logits, f32 cast EXACTLY at softmax input
// (mirrors reference's masked.astype(float32) -> the -1e9 bucket quantization),
// softmax in f32, weights out, f64 attn over the active t-range
__global__ __launch_bounds__(256) void k_attn(const float* __restrict__ x,
                                              const double* __restrict__ center,
                                              const int* __restrict__ x2w,
                                              const int* __restrict__ m2w,
                                              const float* __restrict__ mask,
                                              float* __restrict__ outA,
                                              float* __restrict__ outW) {
    __shared__ double cen_s[512];
    __shared__ int xw_s[512];
    __shared__ float ev[512];
    __shared__ float redf[256];
    __shared__ double redd[256];
    __shared__ int redmin[256], redmax[256];
    int bid = blockIdx.x;
    int b = bid >> 12, mm = bid & 4095;
    int tid = threadIdx.x;
#pragma unroll
    for (int j = 0; j < 2; j++) {
        int t = tid + j * 256;
        cen_s[t] = center[b * TPH + t];
        xw_s[t] = x2w[b * TPH + t];
    }
    __syncthreads();
    int wv = m2w[b * TMEL + mm];
    double ym = (wv > 0) ? 1.0 : 0.0;
    double posd = (double)mm;
    float lv[2];
    float lmax = -3.0e38f;
#pragma unroll
    for (int j = 0; j < 2; j++) {
        int t = tid + j * 256;
        double d = cen_s[t] - posd;
        double lg = -(d * d) / 10.0;
        double f = ((xw_s[t] == wv) ? 1.0 : 0.0) * ym * (double)mask[b * TPH + t];
        double masked = lg - (1.0 - f) * 1.0e9;
        float m32 = (float)masked;                     // the reference's astype(f32)
        lv[j] = m32;
        lmax = fmaxf(lmax, m32);
    }
    redf[tid] = lmax; __syncthreads();
    for (int s = 128; s > 0; s >>= 1) { if (tid < s) redf[tid] = fmaxf(redf[tid], redf[tid + s]); __syncthreads(); }
    float rowmax = redf[0]; __syncthreads();
    double lsum = 0.0;
    int tmin = 512, tmax = -1;
#pragma unroll
    for (int j = 0; j < 2; j++) {
        int t = tid + j * 256;
        float e = expf(__fsub_rn(lv[j], rowmax));
        ev[t] = e;
        lsum += (double)e;
        if (e > 0.f) { tmin = min(tmin, t); tmax = max(tmax, t); }
    }
    redd[tid] = lsum; redmin[tid] = tmin; redmax[tid] = tmax;
    __syncthreads();
    for (int s = 128; s > 0; s >>= 1) {
        if (tid < s) {
            redd[tid] += redd[tid + s];
            redmin[tid] = min(redmin[tid], redmin[tid + s]);
            redmax[tid] = max(redmax[tid], redmax[tid + s]);
        }
        __syncthreads();
    }
    float tot = (float)redd[0];
    int t0 = redmin[0], t1 = redmax[0];
    size_t wbase = (size_t)(b * TMEL + mm) * 512;
#pragma unroll
    for (int j = 0; j < 2; j++) {
        int t = tid + j * 256;
        float wgt = __fdiv_rn(ev[t], tot);
        ev[t] = wgt;
        outW[wbase + t] = wgt;
    }
    __syncthreads();
    double acc = 0.0;
    for (int t = t0; t <= t1; t++) {                   // deterministic t-order
        acc += (double)ev[t] * (double)x[(b * TPH + t) * HCH + tid];
    }
    outA[(size_t)(b * TMEL + mm) * HCH + tid] = (float)acc;
}

extern "C" void kernel_launch(void* const* d_in, const int* in_sizes, int n_in,
                              void* d_out, int out_size, void* d_ws, size_t ws_size,
                              hipStream_t stream) {
    (void)in_sizes; (void)n_in; (void)out_size; (void)ws_size;
    const float* x    = (const float*)d_in[0];
    const float* xm   = (const float*)d_in[1];
    const float* pw1  = (const float*)d_in[2];
    const float* pb1  = (const float*)d_in[3];
    const float* g1   = (const float*)d_in[4];
    const float* be1  = (const float*)d_in[5];
    const float* pw2  = (const float*)d_in[6];
    const float* pb2  = (const float*)d_in[7];
    const float* g2   = (const float*)d_in[8];
    const float* be2  = (const float*)d_in[9];
    const float* pjw  = (const float*)d_in[10];
    const float* pjb  = (const float*)d_in[11];
    const float* gw   = (const float*)d_in[12];
    const float* gb   = (const float*)d_in[13];
    const int*   x2w  = (const int*)d_in[14];
    const int*   m2w  = (const int*)d_in[15];

    double* ws   = (double*)d_ws;
    double* wt1  = ws + OFF_WT1;
    double* wt2  = ws + OFF_WT2;
    double* h1   = ws + OFF_H1;
    double* h2   = ws + OFF_H2;
    double* mbuf = ws + OFF_M;
    double* cen  = ws + OFF_CEN;

    float* outA = (float*)d_out;
    float* outW = outA + (size_t)BATCH * TMEL * HCH;
    float* outM = outW + (size_t)BATCH * TMEL * TPH;

    hipLaunchKernelGGL(k_transpose_w, dim3(2 * KKTOT), dim3(256), 0, stream, pw1, pw2, wt1, wt2);
    hipLaunchKernelGGL(k_conv_gemm<float>, dim3(64, 4), dim3(256), 0, stream, x, xm, wt1, h1);
    hipLaunchKernelGGL(k_ln_relu, dim3(4096), dim3(256), 0, stream, h1, pb1, g1, be1, h1);
    hipLaunchKernelGGL(k_conv_gemm<double>, dim3(64, 4), dim3(256), 0, stream, h1, xm, wt2, h2);
    hipLaunchKernelGGL(k_ln_relu, dim3(4096), dim3(256), 0, stream, h2, pb2, g2, be2, h2);
    hipLaunchKernelGGL(k_m, dim3(4096), dim3(256), 0, stream, x, h2, pjw, pjb, gw, gb, xm, mbuf);
    hipLaunchKernelGGL(k_dur, dim3(BATCH), dim3(512), 0, stream, mbuf, x2w, m2w, cen, outM);
    hipLaunchKernelGGL(k_attn, dim3(BATCH * TMEL), dim3(256), 0, stream, x, cen, x2w, m2w, xm, outA, outW);
}

// Round 4
// 518.014 us; speedup vs baseline: 1.5134x; 1.5134x over previous
//
#include <hip/hip_runtime.h>
#include <math.h>

#define BATCH 8
#define TPH   512
#define TMEL  4096
#define HCH   256
#define WLEN  256
#define KKTOT 1280

// ws offsets (in doubles)
#define OFF_WT1 0          // 1280*256
#define OFF_WT2 327680     // 1280*256
#define OFF_H1  655360     // 4096*256
#define OFF_H2  1703936    // 4096*256
#define OFF_M   2752512    // 4096
#define OFF_CEN 2756608    // 4096
#define OFF_GVH 2760704    // 257

// ---- wave (64-lane) reduction helpers ----
__device__ __forceinline__ double wsum_d(double v) {
#pragma unroll
    for (int o = 32; o > 0; o >>= 1) v += __shfl_xor(v, o);
    return v;
}
__device__ __forceinline__ float wmax_f(float v) {
#pragma unroll
    for (int o = 32; o > 0; o >>= 1) v = fmaxf(v, __shfl_xor(v, o));
    return v;
}
__device__ __forceinline__ int wmin_i(int v) {
#pragma unroll
    for (int o = 32; o > 0; o >>= 1) v = min(v, __shfl_xor(v, o));
    return v;
}
__device__ __forceinline__ int wmax_i(int v) {
#pragma unroll
    for (int o = 32; o > 0; o >>= 1) v = max(v, __shfl_xor(v, o));
    return v;
}

// transpose weights (O,I,K) -> (k*256+i, o), f32 -> f64
__global__ __launch_bounds__(256) void k_transpose_w(const float* __restrict__ w1,
                                                     const float* __restrict__ w2,
                                                     double* __restrict__ wt1,
                                                     double* __restrict__ wt2) {
    int idx = blockIdx.x;
    const float* src; double* dst; int kk;
    if (idx < KKTOT) { src = w1; dst = wt1; kk = idx; }
    else             { src = w2; dst = wt2; kk = idx - KKTOT; }
    int k = kk >> 8, i = kk & 255, o = threadIdx.x;
    dst[kk * HCH + o] = (double)src[o * KKTOT + i * 5 + k];
}

// f64 conv-as-GEMM, split-K x2 (combine via f64 atomicAdd into zeroed out).
// grid (4 c-tiles, 64 m-tiles, 2 K-halves); block 256; 64x64 tile; 4x4 micro.
// Double-buffered LDS with register prefetch (1 barrier per K-tile of 16).
template <typename TS>
__global__ __launch_bounds__(256) void k_conv_gemm(const TS* __restrict__ src,
                                                   const float* __restrict__ mask,
                                                   const double* __restrict__ wT,
                                                   double* __restrict__ out) {
    __shared__ double As[2][16][68];
    __shared__ double Bs[2][16][68];
    int tid = threadIdx.x;
    int ty4 = (tid >> 4) * 4, tx4 = (tid & 15) * 4;
    int c0 = blockIdx.x * 64;
    int m0 = blockIdx.y * 64;
    int kb0 = blockIdx.z * 640;
    const int NT = 40;

    // staging assignments
    int q4 = (tid & 3) * 4;      // A: k-quad
    int m_l = tid >> 2;          // A: row 0..63
    int cB = tid & 63;           // B: col
    int kB0 = tid >> 6;          // B: k base (0..3), rows kB0+4j

    double acc[4][4];
#pragma unroll
    for (int i = 0; i < 4; i++)
#pragma unroll
        for (int j = 0; j < 4; j++) acc[i][j] = 0.0;

    int m = m0 + m_l;
    int mbase = m & ~511, mt = m & 511;

    double av[4], bv[4];

    auto fetch = [&](int kt) {
        int kb = kb0 + kt * 16;
        int k5 = kb >> 8, ci0 = kb & 255;
        int tt = mt + k5 - 2;
        if ((unsigned)tt < 512u) {
            int r = mbase + tt;
            double mk = (double)mask[r];
            const TS* sp = src + (size_t)r * HCH + ci0 + q4;
#pragma unroll
            for (int j = 0; j < 4; j++) av[j] = (double)sp[j] * mk;
        } else {
#pragma unroll
            for (int j = 0; j < 4; j++) av[j] = 0.0;
        }
        const double* wp = wT + (size_t)(kb + kB0) * HCH + c0 + cB;
#pragma unroll
        for (int j = 0; j < 4; j++) bv[j] = wp[(size_t)(j * 4) * HCH];
    };
    auto store = [&](int bf) {
#pragma unroll
        for (int j = 0; j < 4; j++) As[bf][q4 + j][m_l] = av[j];
#pragma unroll
        for (int j = 0; j < 4; j++) Bs[bf][kB0 + j * 4][cB] = bv[j];
    };

    fetch(0);
    store(0);
    __syncthreads();
    int buf = 0;
    for (int kt = 0; kt < NT; kt++) {
        if (kt + 1 < NT) fetch(kt + 1);
#pragma unroll
        for (int k = 0; k < 16; k++) {
            const double2* Ap = (const double2*)&As[buf][k][ty4];
            const double2* Bp = (const double2*)&Bs[buf][k][tx4];
            double2 a01 = Ap[0], a23 = Ap[1];
            double2 b01 = Bp[0], b23 = Bp[1];
            double a[4] = {a01.x, a01.y, a23.x, a23.y};
            double bb[4] = {b01.x, b01.y, b23.x, b23.y};
#pragma unroll
            for (int i = 0; i < 4; i++)
#pragma unroll
                for (int j = 0; j < 4; j++) acc[i][j] += a[i] * bb[j];
        }
        if (kt + 1 < NT) store(buf ^ 1);
        __syncthreads();
        buf ^= 1;
    }
#pragma unroll
    for (int r = 0; r < 4; r++) {
        double* op = out + (size_t)(m0 + (ty4 >> 2) * 4 + r) * HCH + c0 + tx4;
#pragma unroll
        for (int j = 0; j < 4; j++) atomicAdd(&op[j], acc[r][j]);
    }
}

// f64: v = y + bias; channel-LN over 256 (shuffle reductions); relu. In-place OK.
__global__ __launch_bounds__(256) void k_ln_relu(const double* __restrict__ y,
                                                 const float* __restrict__ bias,
                                                 const float* __restrict__ g,
                                                 const float* __restrict__ b,
                                                 double* __restrict__ out) {
    __shared__ double part[4];
    __shared__ double bc;
    int row = blockIdx.x, tid = threadIdx.x;
    int lane = tid & 63, wid = tid >> 6;
    double v = y[row * HCH + tid] + (double)bias[tid];
    double s = wsum_d(v);
    if (lane == 0) part[wid] = s;
    __syncthreads();
    if (tid == 0) bc = (part[0] + part[1] + part[2] + part[3]) * (1.0 / 256.0);
    __syncthreads();
    double mu = bc;
    double w = v - mu;
    s = wsum_d(w * w);
    if (lane == 0) part[wid] = s;
    __syncthreads();
    if (tid == 0) bc = (part[0] + part[1] + part[2] + part[3]) * (1.0 / 256.0);
    __syncthreads();
    double var = bc;
    double o = w * (1.0 / sqrt(var + 1e-4)) * (double)g[tid] + (double)b[tid];
    out[row * HCH + tid] = fmax(o, 0.0);
}

// gvh[i] = sum_c gw[c]*projw[c,i] (f64);  gvh[256] = sum_c gw[c]*projb[c]
__global__ __launch_bounds__(256) void k_gvh(const float* __restrict__ gw,
                                             const float* __restrict__ projw,
                                             const float* __restrict__ projb,
                                             double* __restrict__ gvh) {
    __shared__ double part[4];
    int i = threadIdx.x;
    int lane = i & 63, wid = i >> 6;
    double acc = 0.0;
    for (int c = 0; c < HCH; c++) acc += (double)gw[c] * (double)projw[c * HCH + i];
    gvh[i] = acc;
    double s = wsum_d((double)gw[i] * (double)projb[i]);
    if (lane == 0) part[wid] = s;
    __syncthreads();
    if (i == 0) gvh[256] = part[0] + part[1] + part[2] + part[3];
}

// m[row] = (relu(mask*(<gw,x> + <gvh,h2> + gpb) + gb0) + 1) * mask   (one wave/row)
__global__ __launch_bounds__(256) void k_m2(const float* __restrict__ x,
                                            const double* __restrict__ h2,
                                            const float* __restrict__ gw,
                                            const double* __restrict__ gvh,
                                            const float* __restrict__ gb,
                                            const float* __restrict__ mask,
                                            double* __restrict__ mbuf) {
    int lane = threadIdx.x & 63;
    int row = blockIdx.x * 4 + (threadIdx.x >> 6);
    double acc = 0.0;
#pragma unroll
    for (int j = 0; j < 4; j++) {
        int c = j * 64 + lane;
        acc += (double)gw[c] * (double)x[row * HCH + c];
        acc += gvh[c] * h2[row * HCH + c];
    }
    acc = wsum_d(acc);
    if (lane == 0) {
        double mk = (double)mask[row];
        double g0 = mk * (acc + gvh[256]) + (double)gb[0];
        mbuf[row] = (fmax(g0, 0.0) + 1.0) * mk;
    }
}

// per-batch f64: deterministic dur scatter, mel counts, scale, sequential cumsum
__global__ __launch_bounds__(512) void k_dur(const double* __restrict__ mbuf,
                                             const int* __restrict__ x2w,
                                             const int* __restrict__ m2w,
                                             double* __restrict__ center,
                                             float* __restrict__ out_mword) {
    __shared__ double ms[512];
    __shared__ int xw[512];
    __shared__ double dur[257];
    __shared__ int cntw[257];
    __shared__ double msc[512], cbuf[512];
    int b = blockIdx.x, tid = threadIdx.x;
    if (tid < 257) cntw[tid] = 0;
    ms[tid] = mbuf[b * TPH + tid];
    {
        int w = x2w[b * TPH + tid];
        xw[tid] = max(0, min(256, w));
    }
    __syncthreads();
    for (int j = 0; j < TMEL / 512; j++) {
        int ww = m2w[b * TMEL + tid + j * 512];
        ww = max(0, min(256, ww));
        atomicAdd(&cntw[ww], 1);
    }
    __syncthreads();
    if (tid >= 1 && tid <= 256) {
        double s = 0.0;
        for (int t = 0; t < TPH; t++) {
            if (xw[t] == tid) s += ms[t];
        }
        dur[tid] = s;
        out_mword[b * WLEN + tid - 1] = (float)s;
    }
    __syncthreads();
    {
        int w = xw[tid];
        double sc = (double)cntw[w] / (dur[w] + 1e-4);
        msc[tid] = ms[tid] + (sc - 1.0) * ms[tid];
    }
    __syncthreads();
    if (tid == 0) {
        double run = 0.0;
        for (int t = 0; t < TPH; t++) {
            run += msc[t];
            cbuf[t] = run - msc[t] * 0.5;
        }
    }
    __syncthreads();
    center[b * TPH + tid] = cbuf[tid];
}

// one block per (b, mel) row: f64 logits, f32 cast at softmax input (the reference's
// astype), shuffle reductions, weights out, f64 attn over the active t-range
__global__ __launch_bounds__(256) void k_attn(const float* __restrict__ x,
                                              const double* __restrict__ center,
                                              const int* __restrict__ x2w,
                                              const int* __restrict__ m2w,
                                              const float* __restrict__ mask,
                                              float* __restrict__ outA,
                                              float* __restrict__ outW) {
    __shared__ double cen_s[512];
    __shared__ int xw_s[512];
    __shared__ float ev[512];
    __shared__ float pf[4];
    __shared__ double pd[4];
    __shared__ int pmin[4], pmax[4];
    __shared__ float s_rowmax, s_tot;
    __shared__ int s_t0, s_t1;
    int bid = blockIdx.x;
    int b = bid >> 12, mm = bid & 4095;
    int tid = threadIdx.x;
    int lane = tid & 63, wid = tid >> 6;
#pragma unroll
    for (int j = 0; j < 2; j++) {
        int t = tid + j * 256;
        cen_s[t] = center[b * TPH + t];
        xw_s[t] = x2w[b * TPH + t];
    }
    __syncthreads();
    int wv = m2w[b * TMEL + mm];
    double ym = (wv > 0) ? 1.0 : 0.0;
    double posd = (double)mm;
    float lv[2];
    float lmax = -3.0e38f;
#pragma unroll
    for (int j = 0; j < 2; j++) {
        int t = tid + j * 256;
        double d = cen_s[t] - posd;
        double lg = -(d * d) / 10.0;
        double f = ((xw_s[t] == wv) ? 1.0 : 0.0) * ym * (double)mask[b * TPH + t];
        double masked = lg - (1.0 - f) * 1.0e9;
        float m32 = (float)masked;          // reference's astype(f32)
        lv[j] = m32;
        lmax = fmaxf(lmax, m32);
    }
    lmax = wmax_f(lmax);
    if (lane == 0) pf[wid] = lmax;
    __syncthreads();
    if (tid == 0) s_rowmax = fmaxf(fmaxf(pf[0], pf[1]), fmaxf(pf[2], pf[3]));
    __syncthreads();
    float rowmax = s_rowmax;
    double lsum = 0.0;
    int tmin = 512, tmax = -1;
#pragma unroll
    for (int j = 0; j < 2; j++) {
        int t = tid + j * 256;
        float e = expf(__fsub_rn(lv[j], rowmax));
        ev[t] = e;
        lsum += (double)e;
        if (e > 0.f) { tmin = min(tmin, t); tmax = max(tmax, t); }
    }
    lsum = wsum_d(lsum);
    tmin = wmin_i(tmin);
    tmax = wmax_i(tmax);
    if (lane == 0) { pd[wid] = lsum; pmin[wid] = tmin; pmax[wid] = tmax; }
    __syncthreads();
    if (tid == 0) {
        s_tot = (float)(pd[0] + pd[1] + pd[2] + pd[3]);
        s_t0 = min(min(pmin[0], pmin[1]), min(pmin[2], pmin[3]));
        s_t1 = max(max(pmax[0], pmax[1]), max(pmax[2], pmax[3]));
    }
    __syncthreads();
    float tot = s_tot;
    int t0 = s_t0, t1 = s_t1;
    size_t wbase = (size_t)(b * TMEL + mm) * 512;
#pragma unroll
    for (int j = 0; j < 2; j++) {
        int t = tid + j * 256;
        float wgt = __fdiv_rn(ev[t], tot);
        ev[t] = wgt;
        outW[wbase + t] = wgt;
    }
    __syncthreads();
    double acc = 0.0;
    for (int t = t0; t <= t1; t++) {
        acc += (double)ev[t] * (double)x[(b * TPH + t) * HCH + tid];
    }
    outA[(size_t)(b * TMEL + mm) * HCH + tid] = (float)acc;
}

extern "C" void kernel_launch(void* const* d_in, const int* in_sizes, int n_in,
                              void* d_out, int out_size, void* d_ws, size_t ws_size,
                              hipStream_t stream) {
    (void)in_sizes; (void)n_in; (void)out_size; (void)ws_size;
    const float* x    = (const float*)d_in[0];
    const float* xm   = (const float*)d_in[1];
    const float* pw1  = (const float*)d_in[2];
    const float* pb1  = (const float*)d_in[3];
    const float* g1   = (const float*)d_in[4];
    const float* be1  = (const float*)d_in[5];
    const float* pw2  = (const float*)d_in[6];
    const float* pb2  = (const float*)d_in[7];
    const float* g2   = (const float*)d_in[8];
    const float* be2  = (const float*)d_in[9];
    const float* pjw  = (const float*)d_in[10];
    const float* pjb  = (const float*)d_in[11];
    const float* gw   = (const float*)d_in[12];
    const float* gb   = (const float*)d_in[13];
    const int*   x2w  = (const int*)d_in[14];
    const int*   m2w  = (const int*)d_in[15];

    double* ws   = (double*)d_ws;
    double* wt1  = ws + OFF_WT1;
    double* wt2  = ws + OFF_WT2;
    double* h1   = ws + OFF_H1;
    double* h2   = ws + OFF_H2;
    double* mbuf = ws + OFF_M;
    double* cen  = ws + OFF_CEN;
    double* gvh  = ws + OFF_GVH;

    float* outA = (float*)d_out;
    float* outW = outA + (size_t)BATCH * TMEL * HCH;
    float* outM = outW + (size_t)BATCH * TMEL * TPH;

    hipMemsetAsync(h1, 0, (size_t)TMEL * HCH * sizeof(double), stream);
    hipMemsetAsync(h2, 0, (size_t)TMEL * HCH * sizeof(double), stream);
    hipLaunchKernelGGL(k_transpose_w, dim3(2 * KKTOT), dim3(256), 0, stream, pw1, pw2, wt1, wt2);
    hipLaunchKernelGGL(k_conv_gemm<float>, dim3(4, 64, 2), dim3(256), 0, stream, x, xm, wt1, h1);
    hipLaunchKernelGGL(k_ln_relu, dim3(4096), dim3(256), 0, stream, h1, pb1, g1, be1, h1);
    hipLaunchKernelGGL(k_conv_gemm<double>, dim3(4, 64, 2), dim3(256), 0, stream, h1, xm, wt2, h2);
    hipLaunchKernelGGL(k_ln_relu, dim3(4096), dim3(256), 0, stream, h2, pb2, g2, be2, h2);
    hipLaunchKernelGGL(k_gvh, dim3(1), dim3(256), 0, stream, gw, pjw, pjb, gvh);
    hipLaunchKernelGGL(k_m2, dim3(1024), dim3(256), 0, stream, x, h2, gw, gvh, gb, xm, mbuf);
    hipLaunchKernelGGL(k_dur, dim3(BATCH), dim3(512), 0, stream, mbuf, x2w, m2w, cen, outM);
    hipLaunchKernelGGL(k_attn, dim3(BATCH * TMEL), dim3(256), 0, stream, x, cen, x2w, m2w, xm, outA, outW);
}